// Round 4
// baseline (150.315 us; speedup 1.0000x reference)
//
#include <hip/hip_runtime.h>
#include <cstdint>

#define BB   16
#define NN   1024
#define FIN  128
#define FOUT 64
#define ALPHA_S 0.2f
#define MASK_VAL -1000000000000.0f
#define PSTRIDE 1032   // 1024 + 8 f16 pad

typedef float    f32x4 __attribute__((ext_vector_type(4)));
typedef float    f32x8 __attribute__((ext_vector_type(8)));
typedef _Float16 half8 __attribute__((ext_vector_type(8)));

__device__ inline float wave_max(float v){
  #pragma unroll
  for (int off = 32; off; off >>= 1) v = fmaxf(v, __shfl_xor(v, off, 64));
  return v;
}
__device__ inline float wave_sum(float v){
  #pragma unroll
  for (int off = 32; off; off >>= 1) v += __shfl_xor(v, off, 64);
  return v;
}

// ---------------------------------------------------------------------------
// Kernel 1: h = inp @ W; s1 = h.a1, s2 = h.a2; hT (f16 hi+lo), layout
// hT[b][kk][f][jj] (kk=j>>5, jj=j&31). ONE WAVE per block (64 thr), 8 rows:
// all inp addresses are blockIdx-derived -> provably uniform -> s_load_dwordx8.
// Inner loop: 8 FMA per 1 W load (L1-hot, 256B coalesced).
// ---------------------------------------------------------------------------
__global__ __launch_bounds__(64) void k_proj(const float* __restrict__ inp,
                                             const float* __restrict__ W,
                                             const float* __restrict__ a,
                                             _Float16* __restrict__ hT_hi,
                                             _Float16* __restrict__ hT_lo,
                                             float* __restrict__ s1,
                                             float* __restrict__ s2){
  const int f    = threadIdx.x;            // 0..63
  const int row0 = blockIdx.x * 8;         // 8-aligned -> single (j>>5) group
  const int b    = row0 >> 10;
  const int j0   = row0 & 1023;
  const float* ip = inp + (size_t)row0 * FIN;
  const float a1f = a[f];
  const float a2f = a[FOUT + f];

  float acc[8] = {0.f,0.f,0.f,0.f,0.f,0.f,0.f,0.f};
  #pragma unroll 2
  for (int kc = 0; kc < FIN; kc += 8){
    f32x8 ib[8];
    #pragma unroll
    for (int r = 0; r < 8; ++r)
      ib[r] = *(const f32x8*)(ip + r * FIN + kc);   // uniform addr -> s_load
    #pragma unroll
    for (int k = 0; k < 8; ++k){
      float wf = W[(kc + k) * FOUT + f];            // coalesced 256B, L1-hot
      #pragma unroll
      for (int r = 0; r < 8; ++r)
        acc[r] = fmaf(ib[r][k], wf, acc[r]);
    }
  }

  #pragma unroll
  for (int r = 0; r < 8; ++r){
    float v1 = wave_sum(acc[r] * a1f);
    float v2 = wave_sum(acc[r] * a2f);
    if (f == 0){ s1[row0 + r] = v1; s2[row0 + r] = v2; }
  }

  half8 hv, lv;
  #pragma unroll
  for (int r = 0; r < 8; ++r){
    _Float16 hi = (_Float16)acc[r];
    hv[r] = hi;
    lv[r] = (_Float16)(acc[r] - (float)hi);
  }
  size_t idx = (size_t)b * 65536 + (size_t)(j0 >> 5) * 2048
             + (size_t)f * 32 + (size_t)(j0 & 31);
  *(half8*)(hT_hi + idx) = hv;      // 8 consecutive j -> one 16B store
  *(half8*)(hT_lo + idx) = lv;
}

// ---------------------------------------------------------------------------
// Kernel 2: fused masked-softmax + MFMA aggregation + ELU.
// Block = 256 threads (4 waves), 16 rows of one batch. Grid = 1024.
// Phase A: all 16 adj int4 loads hoisted up-front (memory-level parallelism
//          -> HBM-BW-bound instead of latency-bound); wave-local softmax.
// Phase B: per-wave 16x16 C tile, 32 K-steps x (ds_read_b128 + 2 MFMA f16).
// ---------------------------------------------------------------------------
__global__ __launch_bounds__(256) void k_attn(const int* __restrict__ adj,
                                              const _Float16* __restrict__ hT_hi,
                                              const _Float16* __restrict__ hT_lo,
                                              const float* __restrict__ s1,
                                              const float* __restrict__ s2,
                                              float* __restrict__ out){
  __shared__ _Float16 p_buf[16][PSTRIDE];   // ~33 KB
  __shared__ float inv_l[16];

  const int t = threadIdx.x;
  const int w = t >> 6, lane = t & 63;
  const int b  = blockIdx.x >> 6;
  const int i0 = (blockIdx.x & 63) * 16;

  // s2 for j = lane*16 .. +15 (reused for all 4 rows)
  float s2r[16];
  {
    const float4* s2p = (const float4*)(s2 + b * NN);
    #pragma unroll
    for (int c = 0; c < 4; ++c){
      float4 v = s2p[lane * 4 + c];
      s2r[c * 4 + 0] = v.x; s2r[c * 4 + 1] = v.y;
      s2r[c * 4 + 2] = v.z; s2r[c * 4 + 3] = v.w;
    }
  }

  // ---- Phase A: hoisted adj loads (16 in flight per wave) ----
  const int4* ap0 = (const int4*)(adj + ((size_t)(b * NN + i0 + w * 4)) * NN);
  int4 a_all[4][4];
  #pragma unroll
  for (int rq = 0; rq < 4; ++rq){
    #pragma unroll
    for (int c = 0; c < 4; ++c)
      a_all[rq][c] = ap0[(size_t)rq * (NN / 4) + lane * 4 + c];
  }

  #pragma unroll
  for (int rq = 0; rq < 4; ++rq){
    const int il = w * 4 + rq;
    const int i  = i0 + il;
    const float s1i = s1[b * NN + i];

    float sc[16];
    float mx = -3.0e38f;
    #pragma unroll
    for (int c = 0; c < 4; ++c){
      int4 a4 = a_all[rq][c];
      float e0 = s1i + s2r[c*4+0]; e0 = fmaxf(e0, ALPHA_S * e0);
      float e1 = s1i + s2r[c*4+1]; e1 = fmaxf(e1, ALPHA_S * e1);
      float e2 = s1i + s2r[c*4+2]; e2 = fmaxf(e2, ALPHA_S * e2);
      float e3 = s1i + s2r[c*4+3]; e3 = fmaxf(e3, ALPHA_S * e3);
      sc[c*4+0] = a4.x > 0 ? e0 : MASK_VAL;
      sc[c*4+1] = a4.y > 0 ? e1 : MASK_VAL;
      sc[c*4+2] = a4.z > 0 ? e2 : MASK_VAL;
      sc[c*4+3] = a4.w > 0 ? e3 : MASK_VAL;
      mx = fmaxf(mx, fmaxf(fmaxf(sc[c*4+0], sc[c*4+1]), fmaxf(sc[c*4+2], sc[c*4+3])));
    }
    mx = wave_max(mx);

    float psum = 0.f;
    half8 v0, v1;
    #pragma unroll
    for (int m = 0; m < 8; ++m){
      float p = __expf(sc[m] - mx);
      psum += p;
      v0[m] = (_Float16)p;
    }
    #pragma unroll
    for (int m = 0; m < 8; ++m){
      float p = __expf(sc[8 + m] - mx);
      psum += p;
      v1[m] = (_Float16)p;
    }
    psum = wave_sum(psum);
    if (lane == 0) inv_l[il] = 1.0f / psum;

    _Float16* dst = &p_buf[il][lane * 16];
    *(half8*)(dst)     = v0;
    *(half8*)(dst + 8) = v1;
  }
  __syncthreads();

  // ---- Phase B: C(16x16) per wave; A = p_buf rows, B = hT col tile ----
  const int m16 = lane & 15;
  const int g   = lane >> 4;
  const int c0  = w * 16;
  f32x4 acc = {0.f, 0.f, 0.f, 0.f};
  const _Float16* pa = &p_buf[m16][g * 8];
  const size_t bbase = (size_t)b * 65536 + (size_t)(c0 + m16) * 32 + (size_t)g * 8;

  #pragma unroll 4
  for (int kk = 0; kk < 32; ++kk){
    half8 af = *(const half8*)(pa + kk * 32);
    half8 bh = *(const half8*)(hT_hi + bbase + (size_t)kk * 2048);
    half8 bl = *(const half8*)(hT_lo + bbase + (size_t)kk * 2048);
    acc = __builtin_amdgcn_mfma_f32_16x16x32_f16(af, bh, acc, 0, 0, 0);
    acc = __builtin_amdgcn_mfma_f32_16x16x32_f16(af, bl, acc, 0, 0, 0);
  }

  #pragma unroll
  for (int q = 0; q < 4; ++q){
    const int row = g * 4 + q;              // C layout: col=lane&15, row=g*4+q
    float v = acc[q] * inv_l[row];
    float o = v > 0.f ? v : __expf(v) - 1.0f;   // ELU (alpha=1)
    out[((size_t)(b * NN + i0 + row)) * FOUT + c0 + m16] = o;
  }
}

extern "C" void kernel_launch(void* const* d_in, const int* in_sizes, int n_in,
                              void* d_out, int out_size, void* d_ws, size_t ws_size,
                              hipStream_t stream) {
  (void)in_sizes; (void)n_in; (void)out_size; (void)ws_size;
  const float* inp = (const float*)d_in[0];   // (16,1024,128) fp32
  const int*   adj = (const int*)d_in[1];     // (16,1024,1024) int32
  const float* W   = (const float*)d_in[2];   // (128,64) fp32
  const float* a   = (const float*)d_in[3];   // (128,1) fp32
  float* outp = (float*)d_out;                // (16,1024,64) fp32

  _Float16* hT_hi = (_Float16*)d_ws;                    // 2 MB
  _Float16* hT_lo = hT_hi + (size_t)BB * 65536;         // 2 MB
  float* s1 = (float*)(hT_lo + (size_t)BB * 65536);     // 64 KB
  float* s2 = s1 + BB * NN;                             // 64 KB

  k_proj<<<BB * NN / 8, 64, 0, stream>>>(inp, W, a, hT_hi, hT_lo, s1, s2);
  k_attn<<<BB * (NN / 16), 256, 0, stream>>>(adj, hT_hi, hT_lo, s1, s2, outp);
}

// Round 5
// 128.060 us; speedup vs baseline: 1.1738x; 1.1738x over previous
//
#include <hip/hip_runtime.h>
#include <cstdint>

#define BB   16
#define NN   1024
#define FIN  128
#define FOUT 64
#define ALPHA_S 0.2f

typedef float    f32x4 __attribute__((ext_vector_type(4)));
typedef _Float16 half8 __attribute__((ext_vector_type(8)));

__device__ inline float wave_sum(float v){
  #pragma unroll
  for (int off = 32; off; off >>= 1) v += __shfl_xor(v, off, 64);
  return v;
}

// ---------------------------------------------------------------------------
// Kernel 1: h = inp @ W; s1 = h.a1, s2 = h.a2; hT (f16 hi+lo) in layout
// hT[b][kk][f][jj] (kk=j>>5, jj=j&31).
// 512 blocks x 256 thr; 32 rows/block staged to LDS coalesced; wave w does
// rows w*8..w*8+7 (broadcast ds_read_b128, 4 FMA per W scalar load).
// ---------------------------------------------------------------------------
__global__ __launch_bounds__(256) void k_proj(const float* __restrict__ inp,
                                              const float* __restrict__ W,
                                              const float* __restrict__ a,
                                              _Float16* __restrict__ hT_hi,
                                              _Float16* __restrict__ hT_lo,
                                              float* __restrict__ s1,
                                              float* __restrict__ s2){
  __shared__ float inp_s[32 * FIN];     // 16 KB
  const int t = threadIdx.x;
  const int w = t >> 6, f = t & 63;
  const int row0 = blockIdx.x * 32;

  {
    const float4* gsrc = (const float4*)(inp + (size_t)row0 * FIN);
    float4* ldst = (float4*)inp_s;
    #pragma unroll
    for (int i = 0; i < 4; ++i) ldst[i * 256 + t] = gsrc[i * 256 + t];
  }
  __syncthreads();

  float acc[8] = {0.f,0.f,0.f,0.f,0.f,0.f,0.f,0.f};
  const float* ls = inp_s + w * 8 * FIN;
  #pragma unroll 4
  for (int k4 = 0; k4 < 32; ++k4){
    float w0 = W[(k4 * 4 + 0) * FOUT + f];
    float w1 = W[(k4 * 4 + 1) * FOUT + f];
    float w2 = W[(k4 * 4 + 2) * FOUT + f];
    float w3 = W[(k4 * 4 + 3) * FOUT + f];
    #pragma unroll
    for (int r = 0; r < 8; ++r){
      float4 iv = *(const float4*)(ls + r * FIN + k4 * 4);   // broadcast read
      acc[r] = fmaf(iv.x, w0, acc[r]);
      acc[r] = fmaf(iv.y, w1, acc[r]);
      acc[r] = fmaf(iv.z, w2, acc[r]);
      acc[r] = fmaf(iv.w, w3, acc[r]);
    }
  }

  const float a1f = a[f], a2f = a[FOUT + f];
  const int rbase = row0 + w * 8;
  #pragma unroll
  for (int r = 0; r < 8; ++r){
    float v1 = wave_sum(acc[r] * a1f);
    float v2 = wave_sum(acc[r] * a2f);
    if (f == 0){ s1[rbase + r] = v1; s2[rbase + r] = v2; }
  }

  half8 hv, lv;
  #pragma unroll
  for (int r = 0; r < 8; ++r){
    _Float16 hi = (_Float16)acc[r];
    hv[r] = hi;
    lv[r] = (_Float16)(acc[r] - (float)hi);
  }
  const int b  = row0 >> 10;
  const int j0 = (row0 & 1023) + w * 8;        // 8 consecutive j, one 32-group
  size_t idx = (size_t)b * 65536 + (size_t)(j0 >> 5) * 2048
             + (size_t)f * 32 + (size_t)(j0 & 31);
  *(half8*)(hT_hi + idx) = hv;
  *(half8*)(hT_lo + idx) = lv;
}

// ---------------------------------------------------------------------------
// Kernel 2: single-pass fused GAT attention.
// 1024 blocks x 256 thr. Block = (batch, 16-row tile). Wave w owns j-range
// [w*256, w*256+256) and ALL 64 output cols (4 MFMA C tiles).
// Row max via monotonicity: m = leaky(s1_i + max_{j in adj} s2_j) -> needs
// only adj bitmask (64 bits/lane, registers) + s2 (4 KB LDS) — p never
// touches LDS; it is built directly in A-fragment layout and fed to MFMA.
// Cross-wave: max / l / C-partials reduced via LDS (2 barriers total).
// ---------------------------------------------------------------------------
__global__ __launch_bounds__(256) void k_attn(const int* __restrict__ adj,
                                              const _Float16* __restrict__ hT_hi,
                                              const _Float16* __restrict__ hT_lo,
                                              const float* __restrict__ s1,
                                              const float* __restrict__ s2,
                                              float* __restrict__ out){
  __shared__ float s2_s[NN];            // 4 KB (each wave stages+reads own 1/4)
  __shared__ float redmax[4][16];
  __shared__ float redl[4][16];
  __shared__ float csum[4][1088];       // 4 waves x (16 rows x 68-pad) ~17 KB

  const int t = threadIdx.x;
  const int w = t >> 6, lane = t & 63;
  const int m16 = lane & 15, g = lane >> 4;
  const int b  = blockIdx.x >> 6;
  const int i0 = (blockIdx.x & 63) * 16;
  const int jb = w * 256;

  // stage this wave's s2 chunk (wave-internal lgkmcnt ordering; no barrier)
  *(float4*)&s2_s[jb + lane * 4] = *(const float4*)(s2 + b * NN + jb + lane * 4);

  const float s1i = s1[b * NN + i0 + m16];

  // ---- adj: 16 int4 loads in flight; row i0+m16, cols jb + kk*32 + g*8 ----
  const int* arow = adj + ((size_t)(b * NN + i0 + m16)) * NN + jb + g * 8;
  int4 A0[8], A1[8];
  #pragma unroll
  for (int kk = 0; kk < 8; ++kk){
    A0[kk] = *(const int4*)(arow + kk * 32);
    A1[kk] = *(const int4*)(arow + kk * 32 + 4);
  }

  // ---- bitmask + partial neighbor-max of s2 ----
  unsigned mask_lo = 0u, mask_hi = 0u;
  float mxp = -3.0e38f;
  #pragma unroll
  for (int kk = 0; kk < 8; ++kk){
    float4 sA = *(const float4*)&s2_s[jb + kk * 32 + g * 8];
    float4 sB = *(const float4*)&s2_s[jb + kk * 32 + g * 8 + 4];
    unsigned bits = 0u;
    bits |= (A0[kk].x > 0) ? 1u   : 0u;  mxp = fmaxf(mxp, A0[kk].x > 0 ? sA.x : -3.0e38f);
    bits |= (A0[kk].y > 0) ? 2u   : 0u;  mxp = fmaxf(mxp, A0[kk].y > 0 ? sA.y : -3.0e38f);
    bits |= (A0[kk].z > 0) ? 4u   : 0u;  mxp = fmaxf(mxp, A0[kk].z > 0 ? sA.z : -3.0e38f);
    bits |= (A0[kk].w > 0) ? 8u   : 0u;  mxp = fmaxf(mxp, A0[kk].w > 0 ? sA.w : -3.0e38f);
    bits |= (A1[kk].x > 0) ? 16u  : 0u;  mxp = fmaxf(mxp, A1[kk].x > 0 ? sB.x : -3.0e38f);
    bits |= (A1[kk].y > 0) ? 32u  : 0u;  mxp = fmaxf(mxp, A1[kk].y > 0 ? sB.y : -3.0e38f);
    bits |= (A1[kk].z > 0) ? 64u  : 0u;  mxp = fmaxf(mxp, A1[kk].z > 0 ? sB.z : -3.0e38f);
    bits |= (A1[kk].w > 0) ? 128u : 0u;  mxp = fmaxf(mxp, A1[kk].w > 0 ? sB.w : -3.0e38f);
    if (kk < 4) mask_lo |= bits << (kk * 8);
    else        mask_hi |= bits << ((kk - 4) * 8);
  }

  // row-max: reduce over the 4 lanes sharing m16, then across waves
  mxp = fmaxf(mxp, __shfl_xor(mxp, 16, 64));
  mxp = fmaxf(mxp, __shfl_xor(mxp, 32, 64));
  if (g == 0) redmax[w][m16] = mxp;
  __syncthreads();
  float mxg = fmaxf(fmaxf(redmax[0][m16], redmax[1][m16]),
                    fmaxf(redmax[2][m16], redmax[3][m16]));
  const bool empty = (mxg < -1.0e38f);
  const float xm = s1i + mxg;
  const float mrow = fmaxf(xm, ALPHA_S * xm);   // = max_j score (exact, monotone)

  // ---- Phase 2: p (A-frag, registers) -> 4 col-tile MFMAs, hi+lo ----
  f32x4 acc0 = {0,0,0,0}, acc1 = {0,0,0,0}, acc2 = {0,0,0,0}, acc3 = {0,0,0,0};
  float psum = 0.f;
  const size_t bbase = (size_t)b * 65536 + (size_t)(w * 8) * 2048
                     + (size_t)m16 * 32 + (size_t)g * 8;
  const _Float16* bhp = hT_hi + bbase;
  const _Float16* blp = hT_lo + bbase;

  #pragma unroll
  for (int kk = 0; kk < 8; ++kk){
    float4 sA = *(const float4*)&s2_s[jb + kk * 32 + g * 8];
    float4 sB = *(const float4*)&s2_s[jb + kk * 32 + g * 8 + 4];
    const unsigned bits = (kk < 4) ? (mask_lo >> (kk * 8)) : (mask_hi >> ((kk - 4) * 8));
    const float sv[8] = {sA.x, sA.y, sA.z, sA.w, sB.x, sB.y, sB.z, sB.w};
    half8 af;
    #pragma unroll
    for (int u = 0; u < 8; ++u){
      float x = s1i + sv[u];
      float e = fmaxf(x, ALPHA_S * x);
      float p = __expf(e - mrow);                 // <= 1
      p = ((bits >> u) & 1u) ? p : 0.0f;
      p = empty ? 1.0f : p;                       // all-masked row -> uniform
      psum += p;
      af[u] = (_Float16)p;
    }
    half8 b0h = *(const half8*)(bhp + kk * 2048);
    half8 b1h = *(const half8*)(bhp + kk * 2048 + 512);
    half8 b2h = *(const half8*)(bhp + kk * 2048 + 1024);
    half8 b3h = *(const half8*)(bhp + kk * 2048 + 1536);
    half8 b0l = *(const half8*)(blp + kk * 2048);
    half8 b1l = *(const half8*)(blp + kk * 2048 + 512);
    half8 b2l = *(const half8*)(blp + kk * 2048 + 1024);
    half8 b3l = *(const half8*)(blp + kk * 2048 + 1536);
    acc0 = __builtin_amdgcn_mfma_f32_16x16x32_f16(af, b0h, acc0, 0, 0, 0);
    acc0 = __builtin_amdgcn_mfma_f32_16x16x32_f16(af, b0l, acc0, 0, 0, 0);
    acc1 = __builtin_amdgcn_mfma_f32_16x16x32_f16(af, b1h, acc1, 0, 0, 0);
    acc1 = __builtin_amdgcn_mfma_f32_16x16x32_f16(af, b1l, acc1, 0, 0, 0);
    acc2 = __builtin_amdgcn_mfma_f32_16x16x32_f16(af, b2h, acc2, 0, 0, 0);
    acc2 = __builtin_amdgcn_mfma_f32_16x16x32_f16(af, b2l, acc2, 0, 0, 0);
    acc3 = __builtin_amdgcn_mfma_f32_16x16x32_f16(af, b3h, acc3, 0, 0, 0);
    acc3 = __builtin_amdgcn_mfma_f32_16x16x32_f16(af, b3l, acc3, 0, 0, 0);
  }

  // ---- epilogue: cross-wave l and C reduction, ELU, store ----
  psum += __shfl_xor(psum, 16, 64);
  psum += __shfl_xor(psum, 32, 64);
  if (g == 0) redl[w][m16] = psum;

  #pragma unroll
  for (int q = 0; q < 4; ++q){                   // C: row = g*4+q, col = c*16+m16
    csum[w][(g * 4 + q) * 68 +  0 + m16] = acc0[q];
    csum[w][(g * 4 + q) * 68 + 16 + m16] = acc1[q];
    csum[w][(g * 4 + q) * 68 + 32 + m16] = acc2[q];
    csum[w][(g * 4 + q) * 68 + 48 + m16] = acc3[q];
  }
  __syncthreads();

  const int r  = t >> 4;                         // 0..15
  const int c4 = (t & 15) * 4;                   // 0..60
  f32x4 sum = *(const f32x4*)&csum[0][r * 68 + c4];
  sum += *(const f32x4*)&csum[1][r * 68 + c4];
  sum += *(const f32x4*)&csum[2][r * 68 + c4];
  sum += *(const f32x4*)&csum[3][r * 68 + c4];
  const float linv = 1.0f / (redl[0][r] + redl[1][r] + redl[2][r] + redl[3][r]);
  f32x4 o;
  #pragma unroll
  for (int u = 0; u < 4; ++u){
    float v = sum[u] * linv;
    o[u] = v > 0.f ? v : __expf(v) - 1.0f;       // ELU (alpha=1)
  }
  *(f32x4*)(out + ((size_t)(b * NN + i0 + r)) * FOUT + c4) = o;
}

extern "C" void kernel_launch(void* const* d_in, const int* in_sizes, int n_in,
                              void* d_out, int out_size, void* d_ws, size_t ws_size,
                              hipStream_t stream) {
  (void)in_sizes; (void)n_in; (void)out_size; (void)ws_size;
  const float* inp = (const float*)d_in[0];   // (16,1024,128) fp32
  const int*   adj = (const int*)d_in[1];     // (16,1024,1024) int32
  const float* W   = (const float*)d_in[2];   // (128,64) fp32
  const float* a   = (const float*)d_in[3];   // (128,1) fp32
  float* outp = (float*)d_out;                // (16,1024,64) fp32

  _Float16* hT_hi = (_Float16*)d_ws;                    // 2 MB
  _Float16* hT_lo = hT_hi + (size_t)BB * 65536;         // 2 MB
  float* s1 = (float*)(hT_lo + (size_t)BB * 65536);     // 64 KB
  float* s2 = s1 + BB * NN;                             // 64 KB

  k_proj<<<BB * NN / 32, 256, 0, stream>>>(inp, W, a, hT_hi, hT_lo, s1, s2);
  k_attn<<<BB * (NN / 16), 256, 0, stream>>>(adj, hT_hi, hT_lo, s1, s2, outp);
}

// Round 6
// 114.579 us; speedup vs baseline: 1.3119x; 1.1177x over previous
//
#include <hip/hip_runtime.h>
#include <cstdint>

#define BB   16
#define NN   1024
#define FIN  128
#define FOUT 64
#define ALPHA_S 0.2f

typedef float    f32x4 __attribute__((ext_vector_type(4)));
typedef _Float16 half8 __attribute__((ext_vector_type(8)));
typedef _Float16 half4 __attribute__((ext_vector_type(4)));

// ---------------------------------------------------------------------------
// Kernel 1 (MFMA): h = inp @ W via f16 hi/lo 3-term MFMA (rel err ~2^-22);
// s1 = h.a1, s2 = h.a2 (fp32); hT (f16, hi only) in layout
// hT[b][j>>5][f][j&31].  1024 blocks x 256 thr; block = 16 rows; wave w =
// 16-col tile.  12 MFMA/wave replaces 256 broadcast ds_read_b128/lane.
// ---------------------------------------------------------------------------
__global__ __launch_bounds__(256) void k_proj(const float* __restrict__ inp,
                                              const float* __restrict__ W,
                                              const float* __restrict__ a,
                                              _Float16* __restrict__ hT,
                                              float* __restrict__ s1,
                                              float* __restrict__ s2){
  __shared__ float red1[4][16];
  __shared__ float red2[4][16];
  const int t = threadIdx.x;
  const int w = t >> 6, lane = t & 63;
  const int m16 = lane & 15, g = lane >> 4;
  const int i0 = blockIdx.x * 16;          // global row tile (16 rows)
  const int b  = i0 >> 10;
  const int j0 = i0 & 1023;
  const int c0 = w * 16;                   // this wave's col tile

  const float* arow = inp + (size_t)(i0 + m16) * FIN;

  f32x4 acc = {0.f, 0.f, 0.f, 0.f};
  #pragma unroll
  for (int kk = 0; kk < 4; ++kk){
    const int kbase = kk * 32 + g * 8;
    float4 av0 = *(const float4*)(arow + kbase);
    float4 av1 = *(const float4*)(arow + kbase + 4);
    const float av[8] = {av0.x, av0.y, av0.z, av0.w, av1.x, av1.y, av1.z, av1.w};
    half8 ah, al;
    #pragma unroll
    for (int j = 0; j < 8; ++j){
      _Float16 h = (_Float16)av[j];
      ah[j] = h;
      al[j] = (_Float16)(av[j] - (float)h);
    }
    half8 bh, bl;
    #pragma unroll
    for (int j = 0; j < 8; ++j){
      float wv = W[(kbase + j) * FOUT + c0 + m16];   // L1-hot (W = 32 KB)
      _Float16 h = (_Float16)wv;
      bh[j] = h;
      bl[j] = (_Float16)(wv - (float)h);
    }
    acc = __builtin_amdgcn_mfma_f32_16x16x32_f16(ah, bh, acc, 0, 0, 0);
    acc = __builtin_amdgcn_mfma_f32_16x16x32_f16(ah, bl, acc, 0, 0, 0);
    acc = __builtin_amdgcn_mfma_f32_16x16x32_f16(al, bh, acc, 0, 0, 0);
  }

  // ---- s1/s2 partials: sum over this wave's 16 cols, rows g*4+q ----
  const float a1c = a[c0 + m16];
  const float a2c = a[FOUT + c0 + m16];
  f32x4 p1, p2;
  #pragma unroll
  for (int q = 0; q < 4; ++q){ p1[q] = acc[q] * a1c; p2[q] = acc[q] * a2c; }
  #pragma unroll
  for (int off = 1; off < 16; off <<= 1){
    #pragma unroll
    for (int q = 0; q < 4; ++q){
      p1[q] += __shfl_xor(p1[q], off, 64);
      p2[q] += __shfl_xor(p2[q], off, 64);
    }
  }
  if (m16 == 0){
    #pragma unroll
    for (int q = 0; q < 4; ++q){
      red1[w][g * 4 + q] = p1[q];
      red2[w][g * 4 + q] = p2[q];
    }
  }

  // ---- hT store (hi only): f = c0+m16, j = i0 + g*4 + q ----
  half4 hv;
  #pragma unroll
  for (int q = 0; q < 4; ++q) hv[q] = (_Float16)acc[q];
  size_t idx = (size_t)b * 65536 + (size_t)(j0 >> 5) * 2048
             + (size_t)(c0 + m16) * 32 + (size_t)(j0 & 31) + (size_t)g * 4;
  *(half4*)(hT + idx) = hv;

  __syncthreads();
  if (t < 16){
    s1[i0 + t] = red1[0][t] + red1[1][t] + red1[2][t] + red1[3][t];
    s2[i0 + t] = red2[0][t] + red2[1][t] + red2[2][t] + red2[3][t];
  }
}

// ---------------------------------------------------------------------------
// Kernel 2: single-pass fused GAT attention (hi-only hT).
// 1024 blocks x 256 thr. Block = (batch, 16-row tile). Wave w owns j-range
// [w*256, w*256+256) and all 64 output cols (4 MFMA C tiles).
// Row max via monotonicity of leaky_relu: m = leaky(s1_i + max_{adj} s2_j)
// from adj bitmask (registers) + s2 (4 KB LDS). p built directly in
// A-fragment layout; softmax denominator uses the f16-rounded p.
// ---------------------------------------------------------------------------
__global__ __launch_bounds__(256) void k_attn(const int* __restrict__ adj,
                                              const _Float16* __restrict__ hT,
                                              const float* __restrict__ s1,
                                              const float* __restrict__ s2,
                                              float* __restrict__ out){
  __shared__ float s2_s[NN];            // 4 KB
  __shared__ float redmax[4][16];
  __shared__ float redl[4][16];
  __shared__ float csum[4][1088];       // 4 x (16 rows x 68-pad) ~17 KB

  const int t = threadIdx.x;
  const int w = t >> 6, lane = t & 63;
  const int m16 = lane & 15, g = lane >> 4;
  const int b  = blockIdx.x >> 6;
  const int i0 = (blockIdx.x & 63) * 16;
  const int jb = w * 256;

  // stage this wave's s2 chunk (wave-internal lgkmcnt ordering)
  *(float4*)&s2_s[jb + lane * 4] = *(const float4*)(s2 + b * NN + jb + lane * 4);

  const float s1i = s1[b * NN + i0 + m16];

  // ---- adj: 16 int4 loads in flight; row i0+m16, cols jb + kk*32 + g*8 ----
  const int* arow = adj + ((size_t)(b * NN + i0 + m16)) * NN + jb + g * 8;
  int4 A0[8], A1[8];
  #pragma unroll
  for (int kk = 0; kk < 8; ++kk){
    A0[kk] = *(const int4*)(arow + kk * 32);
    A1[kk] = *(const int4*)(arow + kk * 32 + 4);
  }

  // ---- bitmask + partial neighbor-max of s2 ----
  unsigned mask_lo = 0u, mask_hi = 0u;
  float mxp = -3.0e38f;
  #pragma unroll
  for (int kk = 0; kk < 8; ++kk){
    float4 sA = *(const float4*)&s2_s[jb + kk * 32 + g * 8];
    float4 sB = *(const float4*)&s2_s[jb + kk * 32 + g * 8 + 4];
    unsigned bits = 0u;
    bits |= (A0[kk].x > 0) ? 1u   : 0u;  mxp = fmaxf(mxp, A0[kk].x > 0 ? sA.x : -3.0e38f);
    bits |= (A0[kk].y > 0) ? 2u   : 0u;  mxp = fmaxf(mxp, A0[kk].y > 0 ? sA.y : -3.0e38f);
    bits |= (A0[kk].z > 0) ? 4u   : 0u;  mxp = fmaxf(mxp, A0[kk].z > 0 ? sA.z : -3.0e38f);
    bits |= (A0[kk].w > 0) ? 8u   : 0u;  mxp = fmaxf(mxp, A0[kk].w > 0 ? sA.w : -3.0e38f);
    bits |= (A1[kk].x > 0) ? 16u  : 0u;  mxp = fmaxf(mxp, A1[kk].x > 0 ? sB.x : -3.0e38f);
    bits |= (A1[kk].y > 0) ? 32u  : 0u;  mxp = fmaxf(mxp, A1[kk].y > 0 ? sB.y : -3.0e38f);
    bits |= (A1[kk].z > 0) ? 64u  : 0u;  mxp = fmaxf(mxp, A1[kk].z > 0 ? sB.z : -3.0e38f);
    bits |= (A1[kk].w > 0) ? 128u : 0u;  mxp = fmaxf(mxp, A1[kk].w > 0 ? sB.w : -3.0e38f);
    if (kk < 4) mask_lo |= bits << (kk * 8);
    else        mask_hi |= bits << ((kk - 4) * 8);
  }

  // row-max across the 4 lanes sharing m16, then across waves
  mxp = fmaxf(mxp, __shfl_xor(mxp, 16, 64));
  mxp = fmaxf(mxp, __shfl_xor(mxp, 32, 64));
  if (g == 0) redmax[w][m16] = mxp;
  __syncthreads();
  float mxg = fmaxf(fmaxf(redmax[0][m16], redmax[1][m16]),
                    fmaxf(redmax[2][m16], redmax[3][m16]));
  const bool empty = (mxg < -1.0e38f);
  const float xm = s1i + mxg;
  const float mrow = fmaxf(xm, ALPHA_S * xm);   // exact row max (monotone)

  // ---- Phase 2: p (A-frag, registers) -> 4 col-tile MFMAs (hi only) ----
  f32x4 acc0 = {0,0,0,0}, acc1 = {0,0,0,0}, acc2 = {0,0,0,0}, acc3 = {0,0,0,0};
  float psum = 0.f;
  const size_t bbase = (size_t)b * 65536 + (size_t)(w * 8) * 2048
                     + (size_t)m16 * 32 + (size_t)g * 8;
  const _Float16* bhp = hT + bbase;

  #pragma unroll
  for (int kk = 0; kk < 8; ++kk){
    float4 sA = *(const float4*)&s2_s[jb + kk * 32 + g * 8];
    float4 sB = *(const float4*)&s2_s[jb + kk * 32 + g * 8 + 4];
    const unsigned bits = (kk < 4) ? (mask_lo >> (kk * 8)) : (mask_hi >> ((kk - 4) * 8));
    const float sv[8] = {sA.x, sA.y, sA.z, sA.w, sB.x, sB.y, sB.z, sB.w};
    half8 af;
    #pragma unroll
    for (int u = 0; u < 8; ++u){
      float x = s1i + sv[u];
      float e = fmaxf(x, ALPHA_S * x);
      float p = __expf(e - mrow);                 // <= 1
      p = ((bits >> u) & 1u) ? p : 0.0f;
      p = empty ? 1.0f : p;                       // all-masked row -> uniform
      af[u] = (_Float16)p;
      psum += (float)af[u];                       // denominator == numerator
    }
    half8 b0 = *(const half8*)(bhp + kk * 2048);
    half8 b1 = *(const half8*)(bhp + kk * 2048 + 512);
    half8 b2 = *(const half8*)(bhp + kk * 2048 + 1024);
    half8 b3 = *(const half8*)(bhp + kk * 2048 + 1536);
    acc0 = __builtin_amdgcn_mfma_f32_16x16x32_f16(af, b0, acc0, 0, 0, 0);
    acc1 = __builtin_amdgcn_mfma_f32_16x16x32_f16(af, b1, acc1, 0, 0, 0);
    acc2 = __builtin_amdgcn_mfma_f32_16x16x32_f16(af, b2, acc2, 0, 0, 0);
    acc3 = __builtin_amdgcn_mfma_f32_16x16x32_f16(af, b3, acc3, 0, 0, 0);
  }

  // ---- epilogue: cross-wave l and C reduction, ELU, store ----
  psum += __shfl_xor(psum, 16, 64);
  psum += __shfl_xor(psum, 32, 64);
  if (g == 0) redl[w][m16] = psum;

  #pragma unroll
  for (int q = 0; q < 4; ++q){                   // C: row = g*4+q, col = c*16+m16
    csum[w][(g * 4 + q) * 68 +  0 + m16] = acc0[q];
    csum[w][(g * 4 + q) * 68 + 16 + m16] = acc1[q];
    csum[w][(g * 4 + q) * 68 + 32 + m16] = acc2[q];
    csum[w][(g * 4 + q) * 68 + 48 + m16] = acc3[q];
  }
  __syncthreads();

  const int r  = t >> 4;                         // 0..15
  const int c4 = (t & 15) * 4;                   // 0..60
  f32x4 sum = *(const f32x4*)&csum[0][r * 68 + c4];
  sum += *(const f32x4*)&csum[1][r * 68 + c4];
  sum += *(const f32x4*)&csum[2][r * 68 + c4];
  sum += *(const f32x4*)&csum[3][r * 68 + c4];
  const float linv = 1.0f / (redl[0][r] + redl[1][r] + redl[2][r] + redl[3][r]);
  f32x4 o;
  #pragma unroll
  for (int u = 0; u < 4; ++u){
    float v = sum[u] * linv;
    o[u] = v > 0.f ? v : __expf(v) - 1.0f;       // ELU (alpha=1)
  }
  *(f32x4*)(out + ((size_t)(b * NN + i0 + r)) * FOUT + c4) = o;
}

extern "C" void kernel_launch(void* const* d_in, const int* in_sizes, int n_in,
                              void* d_out, int out_size, void* d_ws, size_t ws_size,
                              hipStream_t stream) {
  (void)in_sizes; (void)n_in; (void)out_size; (void)ws_size;
  const float* inp = (const float*)d_in[0];   // (16,1024,128) fp32
  const int*   adj = (const int*)d_in[1];     // (16,1024,1024) int32
  const float* W   = (const float*)d_in[2];   // (128,64) fp32
  const float* a   = (const float*)d_in[3];   // (128,1) fp32
  float* outp = (float*)d_out;                // (16,1024,64) fp32

  _Float16* hT = (_Float16*)d_ws;                      // 2 MB (hi only)
  float* s1 = (float*)(hT + (size_t)BB * 65536);       // 64 KB
  float* s2 = s1 + BB * NN;                            // 64 KB

  k_proj<<<BB * NN / 16, 256, 0, stream>>>(inp, W, a, hT, s1, s2);
  k_attn<<<BB * (NN / 16), 256, 0, stream>>>(adj, hT, s1, s2, outp);
}